// Round 9
// baseline (203.389 us; speedup 1.0000x reference)
//
#include <hip/hip_runtime.h>

#define NN 4096
#define NE 131072
#define DIN 256
#define DHID 512
#define DOUT 64
#define DCAT 1536
#define NBINS 65536
#define HALF_E 65536

typedef __attribute__((ext_vector_type(8))) short short8;
typedef __attribute__((ext_vector_type(4))) float f32x4;

__device__ inline unsigned short bf16rne(float f){
  unsigned u = __float_as_uint(f);
  unsigned r = u + 0x7FFFu + ((u>>16)&1u);
  return (unsigned short)(r>>16);
}
__device__ inline float bf2f(unsigned short u){ return __uint_as_float(((unsigned)u)<<16); }

// ---------------- Threefry-2x32 (JAX-compatible) ----------------
struct K2 { unsigned a, b; };
__host__ __device__ constexpr unsigned rotl32(unsigned x, unsigned d){ return (x<<d)|(x>>(32u-d)); }
__host__ __device__ constexpr K2 tf2x32(unsigned k0, unsigned k1, unsigned x0, unsigned x1){
  unsigned k2 = k0 ^ k1 ^ 0x1BD11BDAu;
  x0 += k0; x1 += k1;
  x0+=x1; x1=rotl32(x1,13); x1^=x0;
  x0+=x1; x1=rotl32(x1,15); x1^=x0;
  x0+=x1; x1=rotl32(x1,26); x1^=x0;
  x0+=x1; x1=rotl32(x1, 6); x1^=x0;
  x0+=k1; x1+=k2+1u;
  x0+=x1; x1=rotl32(x1,17); x1^=x0;
  x0+=x1; x1=rotl32(x1,29); x1^=x0;
  x0+=x1; x1=rotl32(x1,16); x1^=x0;
  x0+=x1; x1=rotl32(x1,24); x1^=x0;
  x0+=k2; x1+=k0+2u;
  x0+=x1; x1=rotl32(x1,13); x1^=x0;
  x0+=x1; x1=rotl32(x1,15); x1^=x0;
  x0+=x1; x1=rotl32(x1,26); x1^=x0;
  x0+=x1; x1=rotl32(x1, 6); x1^=x0;
  x0+=k0; x1+=k1+3u;
  x0+=x1; x1=rotl32(x1,17); x1^=x0;
  x0+=x1; x1=rotl32(x1,29); x1^=x0;
  x0+=x1; x1=rotl32(x1,16); x1^=x0;
  x0+=x1; x1=rotl32(x1,24); x1^=x0;
  x0+=k1; x1+=k2+4u;
  x0+=x1; x1=rotl32(x1,13); x1^=x0;
  x0+=x1; x1=rotl32(x1,15); x1^=x0;
  x0+=x1; x1=rotl32(x1,26); x1^=x0;
  x0+=x1; x1=rotl32(x1, 6); x1^=x0;
  x0+=k2; x1+=k0+5u;
  return K2{x0,x1};
}
static_assert(tf2x32(0u,0u,0u,2u).a==4146024105u, "threefry mismatch o0");
static_assert(tf2x32(0u,0u,0u,2u).b==2718843009u, "threefry mismatch o1");
static_assert(tf2x32(0u,0u,1u,3u).a==967050713u,  "threefry mismatch o0b");
static_assert(tf2x32(0u,0u,1u,3u).b==1272950319u, "threefry mismatch o1b");

// partitionable threefry (verified passing r4-r8)
constexpr K2 E0 = tf2x32(0u,42u,0u,0u);     // key1
constexpr K2 E1 = tf2x32(0u,42u,0u,1u);     // sub1
constexpr unsigned SK1A = E1.a, SK1B = E1.b;
constexpr K2 F1 = tf2x32(E0.a,E0.b,0u,1u);  // sub2
constexpr unsigned SK2A = F1.a, SK2B = F1.b;

// med buffer: [0]=hstar [1]=base [2]=cnt [3]=lo_cut [4]=rk_cut ; [8..71]=lo, [72..135]=rk
#define MED_CAP 64

// ---------------- conversions (device helper) ----------------
__device__ inline void tconv(const float* __restrict__ src, unsigned short* __restrict__ dst,
                             int R, int C, int r0, int c0){
  __shared__ unsigned short tile[64][72];
  int t = threadIdx.x;
  int tr = t>>2, tc = (t&3)*16;
  #pragma unroll
  for (int u=0;u<16;u++)
    tile[tr][tc+u] = bf16rne(src[(size_t)(r0+tr)*C + c0 + tc + u]);
  __syncthreads();
  unsigned short v[16];
  #pragma unroll
  for (int u=0;u<16;u++) v[u] = tile[tc+u][tr];
  uint4* vv = (uint4*)v;
  uint4* o = (uint4*)&dst[(size_t)(c0+tr)*R + r0 + tc];
  o[0] = vv[0]; o[1] = vv[1];
}

// ---------------- front: keys+hists+degrees+bits (blocks 0..511) + all conversions (512..1911) ----------------
__global__ void front_k(const int* __restrict__ ei,
                        unsigned* __restrict__ keys1, unsigned* __restrict__ keys2,
                        unsigned* __restrict__ hist1, unsigned* __restrict__ hist2,
                        unsigned* __restrict__ indeg, unsigned* __restrict__ outdeg,
                        unsigned* __restrict__ bits,
                        const float* __restrict__ x, unsigned short* __restrict__ x_bf,
                        unsigned short* __restrict__ xT_bf,
                        const float* __restrict__ W0, unsigned short* __restrict__ WT0,
                        const float* __restrict__ W1, unsigned short* __restrict__ WT1,
                        const float* __restrict__ W2, unsigned short* __restrict__ WT2,
                        const float* __restrict__ fcW, unsigned short* __restrict__ fcWT){
  int b = blockIdx.x, t = threadIdx.x;
  if (b < 512){
    unsigned e = b*256u + t;
    K2 r1 = tf2x32(SK1A, SK1B, 0u, e);
    unsigned k1 = r1.a ^ r1.b;
    K2 r2 = tf2x32(SK2A, SK2B, 0u, e);
    unsigned k2 = r2.a ^ r2.b;
    keys1[e] = k1; keys2[e] = k2;
    atomicAdd(&hist1[k1>>16], 1u);
    atomicAdd(&hist2[k2>>16], 1u);
    unsigned s = (unsigned)ei[e], d = (unsigned)ei[NE+e];
    atomicAdd(&outdeg[s], 1u);
    atomicAdd(&indeg[d], 1u);
    atomicOr(&bits[d*128 + (s>>5)], 1u << (s&31));
    if (e < NN) atomicOr(&bits[e*128 + (e>>5)], 1u << (e&31));
    return;
  }
  int b2 = b - 512;
  if (b2 < 1024){                                       // x -> x_bf (flat, 4/thread)
    int i = b2*256 + t;
    float4 f = ((const float4*)x)[i];
    uint2 o;
    o.x = (unsigned)bf16rne(f.x) | ((unsigned)bf16rne(f.y)<<16);
    o.y = (unsigned)bf16rne(f.z) | ((unsigned)bf16rne(f.w)<<16);
    ((uint2*)x_bf)[i] = o;
  } else if (b2 < 1280){                                // x^T: 256 tiles
    int idx = b2 - 1024;
    tconv(x, xT_bf, NN, DIN, (idx>>2)*64, (idx&3)*64);
  } else if (b2 < 1376){                                // 3 enc weights: 32 tiles each
    int idx = b2 - 1280;
    int z = idx >> 5, tl = idx & 31;
    const float* src = z==0?W0 : z==1?W1 : W2;
    unsigned short* dst = z==0?WT0 : z==1?WT1 : WT2;
    tconv(src, dst, DIN, DHID, (tl>>3)*64, (tl&7)*64);
  } else {                                              // fcW: 24 tiles
    int by = b2 - 1376;
    tconv(fcW, fcWT, DCAT, DOUT, by*64, 0);
  }
}

// ---------------- single-launch quad scan (decoupled lookback) + med1 fused ----------------
// y: 0=hist1->prefix1/cursor1, 1=hist2->prefix2/cursor2 (+median bin), 2=indeg->in_off/curin, 3=outdeg->out_off/curout
// flag word: bit31=prefix-valid, bit30=aggregate-valid, [29:0]=value (sums <= 131072)
__global__ void scanAll_k(const unsigned* __restrict__ in0, const unsigned* __restrict__ in1,
                          const unsigned* __restrict__ in2, const unsigned* __restrict__ in3,
                          unsigned* __restrict__ o0, unsigned* __restrict__ o1,
                          unsigned* __restrict__ o2, unsigned* __restrict__ o3,
                          unsigned* __restrict__ c0, unsigned* __restrict__ c1,
                          unsigned* __restrict__ c2, unsigned* __restrict__ c3,
                          unsigned* __restrict__ flags, unsigned* __restrict__ med){
  int y = blockIdx.y;
  int nblk = (y<2) ? (NBINS/256) : (NN/256);
  int xb = blockIdx.x;
  if (xb >= nblk) return;
  const unsigned* in = y==0?in0 : y==1?in1 : y==2?in2 : in3;
  unsigned* o        = y==0?o0  : y==1?o1  : y==2?o2  : o3;
  unsigned* c        = y==0?c0  : y==1?c1  : y==2?c2  : c3;
  __shared__ unsigned s[256];
  __shared__ unsigned base_s;
  int t = threadIdx.x; unsigned i = xb*256u + t;
  unsigned v = in[i]; s[t] = v; __syncthreads();
  for (int off=1; off<256; off<<=1){
    unsigned u = (t>=off)?s[t-off]:0u; __syncthreads();
    s[t]+=u; __syncthreads();
  }
  unsigned excl = s[t]-v;
  unsigned total = s[255];
  if (t==0){
    unsigned* f = flags + y*256;
    if (xb==0){
      atomicExch(&f[0], 0x80000000u | total);
      base_s = 0u;
    } else {
      atomicExch(&f[xb], 0x40000000u | total);
      unsigned base = 0u; int pr = xb-1;
      while (true){
        unsigned fv = atomicAdd(&f[pr], 0u);
        if (fv & 0x80000000u){ base += fv & 0x3FFFFFFFu; break; }
        if (fv & 0x40000000u){ base += fv & 0x3FFFFFFFu; pr--; continue; }
        __builtin_amdgcn_s_sleep(1);
      }
      atomicExch(&f[xb], 0x80000000u | (base + total));
      base_s = base;
    }
  }
  __syncthreads();
  unsigned res = excl + base_s;
  o[i] = res; c[i] = res;
  if (y==1 && res <= HALF_E && HALF_E < res + v){ med[0] = i; med[1] = res; }
}

// ---------------- scat1 + median-bin collection (by direct index: {(k2[r],r)} over all r) ----------------
__global__ void scat1med_k(const unsigned* __restrict__ keys1, const unsigned* __restrict__ keys2,
                           unsigned* __restrict__ cursor, unsigned* __restrict__ slow,
                           unsigned* __restrict__ stb, unsigned* __restrict__ med){
  int e = blockIdx.x*256 + threadIdx.x;
  unsigned k = keys1[e];
  unsigned p = atomicAdd(&cursor[k>>16], 1u);
  slow[p] = k & 0xFFFFu; stb[p] = (unsigned)e;
  unsigned k2 = keys2[e];
  if ((k2>>16) == med[0]){
    unsigned idx = atomicAdd(&med[2], 1u);
    if (idx < MED_CAP){ med[8+idx] = k2 & 0xFFFFu; med[72+idx] = (unsigned)e; }
  }
}

// ---------------- rank1 (blocks 0..EB-1) + med3 cut-selection (block EB) ----------------
__global__ void rank1med_k(const unsigned* __restrict__ keys1, const unsigned* __restrict__ prefix,
                           const unsigned* __restrict__ hist, const unsigned* __restrict__ slow,
                           const unsigned* __restrict__ stb, unsigned* __restrict__ rank1,
                           unsigned* __restrict__ med){
  int b = blockIdx.x, t = threadIdx.x;
  if (b == NE/256){
    unsigned n = med[2]; if (n > MED_CAP) n = MED_CAP;
    unsigned qcut = HALF_E - med[1];
    if (t < (int)n){
      unsigned lo = med[8+t], rk = med[72+t], pos = 0;
      for (unsigned j=0;j<n;j++){
        unsigned lj = med[8+j], rj = med[72+j];
        if (lj < lo || (lj==lo && rj < rk)) pos++;
      }
      if (pos == qcut){ med[3] = lo; med[4] = rk; }
    }
    return;
  }
  int e = b*256 + t;
  unsigned k = keys1[e], h = k>>16, lo = k & 0xFFFFu, tb = (unsigned)e;
  unsigned base = prefix[h], n = hist[h], r = 0;
  for (unsigned j=0;j<n;j++){
    unsigned l2 = slow[base+j], t2 = stb[base+j];
    if (l2 < lo || (l2==lo && t2 < tb)) r++;
  }
  rank1[e] = base + r;
}

// ---------------- CSR scatter + inline keep ----------------
__global__ void scatter_edges_k(const int* __restrict__ ei, const unsigned* __restrict__ rank1,
                                const unsigned* __restrict__ keys2, const unsigned* __restrict__ med,
                                unsigned* __restrict__ curin, unsigned* __restrict__ curout,
                                unsigned* __restrict__ in_list, unsigned* __restrict__ out_list){
  int e = blockIdx.x*256 + threadIdx.x;
  unsigned s = (unsigned)ei[e], d = (unsigned)ei[NE+e];
  unsigned rk = rank1[e], k2 = keys2[rk];
  unsigned h = k2>>16, lo = k2 & 0xFFFFu;
  unsigned hs = med[0], loc = med[3], rkc = med[4];
  unsigned keep = (h > hs) || (h == hs && (lo > loc || (lo == loc && rk >= rkc)));
  unsigned p = atomicAdd(&curin[d], 1u);  in_list[p] = s;
  unsigned q = atomicAdd(&curout[s], 1u); out_list[q] = d | (keep<<31);
}

// ---------------- 2-hop reach+popcount (blocks 0..4095) + cut feature (blocks 4096..8191) ----------------
__global__ void reachcut_k(const unsigned* __restrict__ bits, const unsigned* __restrict__ in_off,
                           const unsigned* __restrict__ in_list, const unsigned* __restrict__ indeg,
                           unsigned* __restrict__ reach, float* __restrict__ cntinv,
                           const float* __restrict__ x, const unsigned* __restrict__ out_off,
                           const unsigned* __restrict__ outdeg, const unsigned* __restrict__ out_list,
                           unsigned short* __restrict__ cut_bf){
  int b = blockIdx.x, t = threadIdx.x;
  if (b < NN){
    __shared__ int ws4[4];
    int i = b;
    int c = 0;
    if (t < 128){
      unsigned off = in_off[i], deg = indeg[i];
      unsigned acc = bits[i*128 + t];
      for (unsigned j=0;j<deg;j++) acc |= bits[in_list[off+j]*128 + t];
      reach[i*128 + t] = acc;
      c = __popc(acc);
    }
    for (int o=32;o>0;o>>=1) c += __shfl_xor(c, o, 64);
    if ((t&63)==0) ws4[t>>6] = c;
    __syncthreads();
    if (t==0) cntinv[i] = 1.0f / (float)(ws4[0]+ws4[1]+ws4[2]+ws4[3]);
  } else {
    int s = b - NN;
    unsigned off = out_off[s], deg = outdeg[s];
    float acc = 0.f; int cnt = 0;
    for (unsigned j=0;j<deg;j++){
      unsigned p = out_list[off+j];
      if (p >> 31){ cnt++; acc += x[(p & 0xFFFFu)*DIN + t]; }
    }
    float v = cnt ? acc / (float)cnt : x[s*DIN + t];
    cut_bf[(size_t)s*DIN + t] = bf16rne(v);
  }
}

// ---------------- ego bit-GEMM, split-K=4, K_STEP=128 ----------------
__global__ void bitgemm_k(const unsigned* __restrict__ reach, const unsigned short* __restrict__ xT,
                          float* __restrict__ pbuf){
  __shared__ __align__(16) unsigned short bt[4][64*32];
  int t = threadIdx.x, w = t>>6, l = t&63;
  int m0 = blockIdx.x*64, n0 = blockIdx.y*64;
  int kbase = blockIdx.z*(NN/4);
  int srow = t>>2, sg = t&3;
  int arow = m0 + 16*w + (l&15);
  int lg = l>>4;
  f32x4 acc[4];
  #pragma unroll
  for (int c=0;c<4;c++) acc[c] = f32x4{0.f,0.f,0.f,0.f};

  for (int it=0; it<8; ++it){
    int kk = kbase + it*128;
    __syncthreads();
    #pragma unroll
    for (int s=0;s<4;s++){
      uint4 v = *(const uint4*)&xT[(size_t)(n0+srow)*NN + kk + 32*s + sg*8];
      *(uint4*)&bt[s][srow*32 + ((sg ^ (srow&3))*8)] = v;
    }
    __syncthreads();
    unsigned rw[4];
    *(uint4*)rw = *(const uint4*)&reach[(size_t)arow*128 + (kk>>5)];
    #pragma unroll
    for (int s=0;s<4;s++){
      unsigned byte = (rw[s] >> (8*lg)) & 0xFFu;
      union { short8 s8; unsigned u[4]; } af;
      #pragma unroll
      for (int pp=0;pp<4;pp++){
        unsigned b0 = (byte>>(2*pp))&1u, b1 = (byte>>(2*pp+1))&1u;
        af.u[pp] = b0*0x3F80u | b1*0x3F800000u;
      }
      #pragma unroll
      for (int c=0;c<4;c++){
        int brow = 16*c + (l&15);
        short8 bf = *(const short8*)&bt[s][brow*32 + ((lg ^ (brow&3))*8)];
        acc[c] = __builtin_amdgcn_mfma_f32_16x16x32_bf16(af.s8, bf, acc[c], 0,0,0);
      }
    }
  }
  size_t zoff = (size_t)blockIdx.z*NN*DIN;
  #pragma unroll
  for (int c=0;c<4;c++){
    #pragma unroll
    for (int r=0;r<4;r++){
      int row = m0 + 16*w + 4*lg + r;
      int col = n0 + 16*c + (l&15);
      pbuf[zoff + (size_t)row*DIN + col] = acc[c][r];
    }
  }
}

// ---------------- reduce partials + scale -> ego_bf ----------------
__global__ void redscale_k(const float* __restrict__ pbuf, const float* __restrict__ cntinv,
                           unsigned short* __restrict__ ego_bf){
  int g = blockIdx.x*256 + threadIdx.x;
  const size_t S = (size_t)NN*DIN/4;
  const float4* p4 = (const float4*)pbuf;
  float4 a = p4[g], b = p4[g+S], c = p4[g+2*S], d = p4[g+3*S];
  int row = (g*4)>>8;
  float ci = cntinv[row];
  float vx = (a.x+b.x+c.x+d.x)*ci, vy = (a.y+b.y+c.y+d.y)*ci;
  float vz = (a.z+b.z+c.z+d.z)*ci, vw = (a.w+b.w+c.w+d.w)*ci;
  uint2 o;
  o.x = (unsigned)bf16rne(vx) | ((unsigned)bf16rne(vy)<<16);
  o.y = (unsigned)bf16rne(vz) | ((unsigned)bf16rne(vw)<<16);
  ((uint2*)ego_bf)[g] = o;
}

// ---------------- aggregate 256-dim features over in-edges (linearity trick) ----------------
__global__ void aggfeat_k(const unsigned short* __restrict__ ego_bf, const unsigned short* __restrict__ cut_bf,
                          const unsigned* __restrict__ in_off, const unsigned* __restrict__ indeg,
                          const unsigned* __restrict__ in_list,
                          unsigned short* __restrict__ aggE, unsigned short* __restrict__ aggC){
  int i = blockIdx.x, t = threadIdx.x;
  unsigned off = in_off[i], deg = indeg[i];
  float ae = 0.f, ac = 0.f;
  for (unsigned j=0;j<deg;j++){
    unsigned s = in_list[off+j];
    ae += bf2f(ego_bf[(size_t)s*DIN + t]);
    ac += bf2f(cut_bf[(size_t)s*DIN + t]);
  }
  aggE[(size_t)i*DIN + t] = bf16rne(ae);
  aggC[(size_t)i*DIN + t] = bf16rne(ac);
}

// ---------------- merged encoder GEMM (z: 0=ego-agg,1=cut-agg,2=glob) ----------------
__global__ void gemm3_k(const unsigned short* __restrict__ aggE, const unsigned short* __restrict__ aggC,
                        const unsigned short* __restrict__ xbf,
                        const unsigned short* __restrict__ WTe, const unsigned short* __restrict__ WTc,
                        const unsigned short* __restrict__ WTg,
                        const float* __restrict__ eb, const float* __restrict__ cb, const float* __restrict__ gb,
                        const unsigned* __restrict__ indeg, unsigned short* __restrict__ hcat){
  __shared__ __align__(16) unsigned short at[4][64*32];
  __shared__ __align__(16) unsigned short bt[4][64*32];
  int z = blockIdx.z;
  const unsigned short* A  = z==0? aggE : z==1? aggC : xbf;
  const unsigned short* BT = z==0? WTe  : z==1? WTc  : WTg;
  const float* bias        = z==0? eb   : z==1? cb   : gb;
  int t = threadIdx.x, w = t>>6, l = t&63;
  int n0 = blockIdx.x*64, m0 = blockIdx.y*64;
  int srow = t>>2, sg = t&3;
  int lg = l>>4;
  f32x4 acc[4];
  #pragma unroll
  for (int c=0;c<4;c++) acc[c] = f32x4{0.f,0.f,0.f,0.f};

  for (int it=0; it<2; ++it){
    int kk = it*128;
    __syncthreads();
    #pragma unroll
    for (int s=0;s<4;s++){
      uint4 va = *(const uint4*)&A [(size_t)(m0+srow)*DIN + kk + 32*s + sg*8];
      uint4 vb = *(const uint4*)&BT[(size_t)(n0+srow)*DIN + kk + 32*s + sg*8];
      *(uint4*)&at[s][srow*32 + ((sg ^ (srow&3))*8)] = va;
      *(uint4*)&bt[s][srow*32 + ((sg ^ (srow&3))*8)] = vb;
    }
    __syncthreads();
    int ar = 16*w + (l&15);
    #pragma unroll
    for (int s=0;s<4;s++){
      short8 af = *(const short8*)&at[s][ar*32 + ((lg ^ (ar&3))*8)];
      #pragma unroll
      for (int c=0;c<4;c++){
        int brow = 16*c + (l&15);
        short8 bf = *(const short8*)&bt[s][brow*32 + ((lg ^ (brow&3))*8)];
        acc[c] = __builtin_amdgcn_mfma_f32_16x16x32_bf16(af, bf, acc[c], 0,0,0);
      }
    }
  }
  #pragma unroll
  for (int c=0;c<4;c++){
    #pragma unroll
    for (int r=0;r<4;r++){
      int row = m0 + 16*w + 4*lg + r;
      int col = n0 + 16*c + (l&15);
      float scale = (z<2) ? (float)indeg[row] : 1.0f;
      float v = acc[c][r] + bias[col]*scale;
      if (z<2) v = fmaxf(v, 0.f);
      hcat[(size_t)row*DCAT + z*DHID + col] = bf16rne(v);
    }
  }
}

// ---------------- fc GEMM split-K=4 ----------------
__global__ void fcgemm_k(const unsigned short* __restrict__ hcat, const unsigned short* __restrict__ fcWT,
                         float* __restrict__ fcpart){
  __shared__ __align__(16) unsigned short at[4][64*32];
  __shared__ __align__(16) unsigned short bt[4][64*32];
  int t = threadIdx.x, w = t>>6, l = t&63;
  int m0 = blockIdx.x*64;
  int kbase = blockIdx.y*(DCAT/4);
  int srow = t>>2, sg = t&3;
  int lg = l>>4;
  f32x4 acc[4];
  #pragma unroll
  for (int c=0;c<4;c++) acc[c] = f32x4{0.f,0.f,0.f,0.f};

  for (int it=0; it<3; ++it){
    int kk = kbase + it*128;
    __syncthreads();
    #pragma unroll
    for (int s=0;s<4;s++){
      uint4 va = *(const uint4*)&hcat [(size_t)(m0+srow)*DCAT + kk + 32*s + sg*8];
      uint4 vb = *(const uint4*)&fcWT[(size_t)srow*DCAT + kk + 32*s + sg*8];
      *(uint4*)&at[s][srow*32 + ((sg ^ (srow&3))*8)] = va;
      *(uint4*)&bt[s][srow*32 + ((sg ^ (srow&3))*8)] = vb;
    }
    __syncthreads();
    int ar = 16*w + (l&15);
    #pragma unroll
    for (int s=0;s<4;s++){
      short8 af = *(const short8*)&at[s][ar*32 + ((lg ^ (ar&3))*8)];
      #pragma unroll
      for (int c=0;c<4;c++){
        int brow = 16*c + (l&15);
        short8 bf = *(const short8*)&bt[s][brow*32 + ((lg ^ (brow&3))*8)];
        acc[c] = __builtin_amdgcn_mfma_f32_16x16x32_bf16(af, bf, acc[c], 0,0,0);
      }
    }
  }
  size_t zoff = (size_t)blockIdx.y*NN*DOUT;
  #pragma unroll
  for (int c=0;c<4;c++){
    #pragma unroll
    for (int r=0;r<4;r++){
      int row = m0 + 16*w + 4*lg + r;
      int col = 16*c + (l&15);
      fcpart[zoff + (size_t)row*DOUT + col] = acc[c][r];
    }
  }
}

// ---------------- finish: sum partials + bias + log_softmax ----------------
__global__ void fcfin_k(const float* __restrict__ fcpart, const float* __restrict__ fcb,
                        float* __restrict__ out){
  int i = blockIdx.x, l = threadIdx.x;
  const size_t S = (size_t)NN*DOUT;
  size_t idx = (size_t)i*DOUT + l;
  float v = fcpart[idx] + fcpart[idx+S] + fcpart[idx+2*S] + fcpart[idx+3*S] + fcb[l];
  float m = v;
  for (int o=32;o>0;o>>=1) m = fmaxf(m, __shfl_xor(m, o, 64));
  float e = __expf(v - m), s = e;
  for (int o=32;o>0;o>>=1) s += __shfl_xor(s, o, 64);
  out[idx] = (v - m) - logf(s);
}

// ---------------- host launch ----------------
static inline size_t alignup(size_t x){ return (x + 255) & ~(size_t)255; }

extern "C" void kernel_launch(void* const* d_in, const int* in_sizes, int n_in,
                              void* d_out, int out_size, void* d_ws, size_t ws_size,
                              hipStream_t stream) {
  const float* x      = (const float*)d_in[0];
  const int*   ei     = (const int*)  d_in[1];
  const float* ego_W  = (const float*)d_in[2];
  const float* ego_b  = (const float*)d_in[3];
  const float* cut_W  = (const float*)d_in[4];
  const float* cut_b  = (const float*)d_in[5];
  const float* glob_W = (const float*)d_in[6];
  const float* glob_b = (const float*)d_in[7];
  const float* fc_W   = (const float*)d_in[8];
  const float* fc_b   = (const float*)d_in[9];
  float* out = (float*)d_out;

  char* base = (char*)d_ws;
  char* p = base;
  #define ALLOC(ty, name, cnt) ty* name = (ty*)p; p += alignup(sizeof(ty)*(size_t)(cnt));
  ALLOC(char,           R0,      (size_t)4*NN*DIN*4);   // 16MB: sort temps -> pbuf -> hcat
  // ---- zero region (one memset) ----
  ALLOC(unsigned,       bits,    NN*128);
  ALLOC(unsigned,       indeg,   NN);
  ALLOC(unsigned,       outdeg,  NN);
  ALLOC(unsigned,       hist1,   NBINS);
  ALLOC(unsigned,       hist2,   NBINS);
  ALLOC(unsigned,       med,     256);
  ALLOC(unsigned,       flags,   1024);
  char* zero_end = p;
  // ---- rest ----
  ALLOC(unsigned,       in_off,  NN);
  ALLOC(unsigned,       out_off, NN);
  ALLOC(unsigned,       curin,   NN);
  ALLOC(unsigned,       curout,  NN);
  ALLOC(unsigned,       in_list, NE);
  ALLOC(unsigned,       out_list,NE);
  ALLOC(unsigned,       reach,   NN*128);
  ALLOC(float,          cntinv,  NN);
  ALLOC(unsigned short, x_bf,    (size_t)NN*DIN);
  ALLOC(unsigned short, xT_bf,   (size_t)DIN*NN);
  ALLOC(unsigned short, ego_bf,  (size_t)NN*DIN);
  ALLOC(unsigned short, cut_bf,  (size_t)NN*DIN);
  ALLOC(unsigned short, aggE_bf, (size_t)NN*DIN);
  ALLOC(unsigned short, aggC_bf, (size_t)NN*DIN);
  ALLOC(unsigned short, egoWT,   (size_t)DHID*DIN);
  ALLOC(unsigned short, cutWT,   (size_t)DHID*DIN);
  ALLOC(unsigned short, globWT,  (size_t)DHID*DIN);
  ALLOC(unsigned short, fcWT,    (size_t)DOUT*DCAT);
  ALLOC(unsigned,       prefix1, NBINS);
  ALLOC(unsigned,       cursor1, NBINS);
  ALLOC(unsigned,       prefix2, NBINS);
  ALLOC(unsigned,       cursor2, NBINS);
  ALLOC(float,          fcpart,  (size_t)4*NN*DOUT);
  #undef ALLOC
  size_t need = (size_t)(p - base);
  if (ws_size < need){
    hipMemsetAsync(d_out, 0x7F, (size_t)out_size*sizeof(float), stream);
    return;
  }
  float*          pbuf = (float*)R0;
  unsigned short* hcat = (unsigned short*)R0;
  char* q = R0;
  #define OALLOC(ty, name, cnt) ty* name = (ty*)q; q += alignup(sizeof(ty)*(size_t)(cnt));
  OALLOC(unsigned, keys1,  NE);
  OALLOC(unsigned, keys2,  NE);
  OALLOC(unsigned, rank1,  NE);
  OALLOC(unsigned, slow,   NE);
  OALLOC(unsigned, stb,    NE);
  #undef OALLOC

  const int EB = NE/256;

  // 1) zero [bits|indeg|outdeg|hist1|hist2|med|flags]
  hipMemsetAsync(bits, 0, (size_t)(zero_end - (char*)bits), stream);
  // 2) keys + hists + degrees + bits, fused with ALL conversions
  hipLaunchKernelGGL(front_k, dim3(1912), dim3(256), 0, stream,
                     ei, keys1, keys2, hist1, hist2, indeg, outdeg, bits,
                     x, x_bf, xT_bf, ego_W, egoWT, cut_W, cutWT, glob_W, globWT, fc_W, fcWT);
  // 3) quad scan (decoupled lookback) + median-bin locate
  hipLaunchKernelGGL(scanAll_k, dim3(NBINS/256, 4), dim3(256), 0, stream,
                     hist1, hist2, indeg, outdeg,
                     prefix1, prefix2, in_off, out_off,
                     cursor1, cursor2, curin, curout, flags, med);
  // 4) round-1 binned scatter + median-bin member collection
  hipLaunchKernelGGL(scat1med_k, dim3(EB), dim3(256), 0, stream,
                     keys1, keys2, cursor1, slow, stb, med);
  // 5) round-1 rank + cut-element selection
  hipLaunchKernelGGL(rank1med_k, dim3(EB+1), dim3(256), 0, stream,
                     keys1, prefix1, hist1, slow, stb, rank1, med);
  // 6) CSR scatter + inline keep
  hipLaunchKernelGGL(scatter_edges_k, dim3(EB), dim3(256), 0, stream,
                     ei, rank1, keys2, med, curin, curout, in_list, out_list);
  // 7) 2-hop reach + cut feature
  hipLaunchKernelGGL(reachcut_k, dim3(2*NN), dim3(256), 0, stream,
                     bits, in_off, in_list, indeg, reach, cntinv,
                     x, out_off, outdeg, out_list, cut_bf);
  // 8) ego bit-GEMM (pbuf overlays sort temps; keys2/rank1 dead after step 6)
  hipLaunchKernelGGL(bitgemm_k, dim3(NN/64, DIN/64, 4), dim3(256), 0, stream, reach, xT_bf, pbuf);
  // 9) reduce partials + scale
  hipLaunchKernelGGL(redscale_k, dim3((NN*DIN/4)/256), dim3(256), 0, stream, pbuf, cntinv, ego_bf);
  // 10) feature aggregation (linearity trick)
  hipLaunchKernelGGL(aggfeat_k, dim3(NN), dim3(256), 0, stream,
                     ego_bf, cut_bf, in_off, indeg, in_list, aggE_bf, aggC_bf);
  // 11) encoders -> hcat (overlays pbuf, dead after 9)
  hipLaunchKernelGGL(gemm3_k, dim3(DHID/64, NN/64, 3), dim3(256), 0, stream,
                     aggE_bf, aggC_bf, x_bf, egoWT, cutWT, globWT,
                     ego_b, cut_b, glob_b, indeg, hcat);
  // 12-13) fc + log_softmax
  hipLaunchKernelGGL(fcgemm_k, dim3(NN/64, 4), dim3(256), 0, stream, hcat, fcWT, fcpart);
  hipLaunchKernelGGL(fcfin_k, dim3(NN), dim3(64), 0, stream, fcpart, fc_b, out);
}

// Round 10
// 199.602 us; speedup vs baseline: 1.0190x; 1.0190x over previous
//
#include <hip/hip_runtime.h>

#define NN 4096
#define NE 131072
#define DIN 256
#define DHID 512
#define DOUT 64
#define DCAT 1536
#define NBINS 65536
#define HALF_E 65536

typedef __attribute__((ext_vector_type(8))) short short8;
typedef __attribute__((ext_vector_type(4))) float f32x4;

__device__ inline unsigned short bf16rne(float f){
  unsigned u = __float_as_uint(f);
  unsigned r = u + 0x7FFFu + ((u>>16)&1u);
  return (unsigned short)(r>>16);
}
__device__ inline float bf2f(unsigned short u){ return __uint_as_float(((unsigned)u)<<16); }

// ---------------- Threefry-2x32 (JAX-compatible) ----------------
struct K2 { unsigned a, b; };
__host__ __device__ constexpr unsigned rotl32(unsigned x, unsigned d){ return (x<<d)|(x>>(32u-d)); }
__host__ __device__ constexpr K2 tf2x32(unsigned k0, unsigned k1, unsigned x0, unsigned x1){
  unsigned k2 = k0 ^ k1 ^ 0x1BD11BDAu;
  x0 += k0; x1 += k1;
  x0+=x1; x1=rotl32(x1,13); x1^=x0;
  x0+=x1; x1=rotl32(x1,15); x1^=x0;
  x0+=x1; x1=rotl32(x1,26); x1^=x0;
  x0+=x1; x1=rotl32(x1, 6); x1^=x0;
  x0+=k1; x1+=k2+1u;
  x0+=x1; x1=rotl32(x1,17); x1^=x0;
  x0+=x1; x1=rotl32(x1,29); x1^=x0;
  x0+=x1; x1=rotl32(x1,16); x1^=x0;
  x0+=x1; x1=rotl32(x1,24); x1^=x0;
  x0+=k2; x1+=k0+2u;
  x0+=x1; x1=rotl32(x1,13); x1^=x0;
  x0+=x1; x1=rotl32(x1,15); x1^=x0;
  x0+=x1; x1=rotl32(x1,26); x1^=x0;
  x0+=x1; x1=rotl32(x1, 6); x1^=x0;
  x0+=k0; x1+=k1+3u;
  x0+=x1; x1=rotl32(x1,17); x1^=x0;
  x0+=x1; x1=rotl32(x1,29); x1^=x0;
  x0+=x1; x1=rotl32(x1,16); x1^=x0;
  x0+=x1; x1=rotl32(x1,24); x1^=x0;
  x0+=k1; x1+=k2+4u;
  x0+=x1; x1=rotl32(x1,13); x1^=x0;
  x0+=x1; x1=rotl32(x1,15); x1^=x0;
  x0+=x1; x1=rotl32(x1,26); x1^=x0;
  x0+=x1; x1=rotl32(x1, 6); x1^=x0;
  x0+=k2; x1+=k0+5u;
  return K2{x0,x1};
}
static_assert(tf2x32(0u,0u,0u,2u).a==4146024105u, "threefry mismatch o0");
static_assert(tf2x32(0u,0u,0u,2u).b==2718843009u, "threefry mismatch o1");
static_assert(tf2x32(0u,0u,1u,3u).a==967050713u,  "threefry mismatch o0b");
static_assert(tf2x32(0u,0u,1u,3u).b==1272950319u, "threefry mismatch o1b");

// partitionable threefry (verified passing r4-r9)
constexpr K2 E0 = tf2x32(0u,42u,0u,0u);     // key1
constexpr K2 E1 = tf2x32(0u,42u,0u,1u);     // sub1
constexpr unsigned SK1A = E1.a, SK1B = E1.b;
constexpr K2 F1 = tf2x32(E0.a,E0.b,0u,1u);  // sub2
constexpr unsigned SK2A = F1.a, SK2B = F1.b;

// med buffer: [0]=hstar [1]=base [2]=cnt [3]=lo_cut [4]=rk_cut ; [8..71]=lo, [72..135]=rk
#define MED_CAP 64

// ---------------- conversions (device helper) ----------------
__device__ inline void tconv(const float* __restrict__ src, unsigned short* __restrict__ dst,
                             int R, int C, int r0, int c0){
  __shared__ unsigned short tile[64][72];
  int t = threadIdx.x;
  int tr = t>>2, tc = (t&3)*16;
  #pragma unroll
  for (int u=0;u<16;u++)
    tile[tr][tc+u] = bf16rne(src[(size_t)(r0+tr)*C + c0 + tc + u]);
  __syncthreads();
  unsigned short v[16];
  #pragma unroll
  for (int u=0;u<16;u++) v[u] = tile[tc+u][tr];
  uint4* vv = (uint4*)v;
  uint4* o = (uint4*)&dst[(size_t)(c0+tr)*R + r0 + tc];
  o[0] = vv[0]; o[1] = vv[1];
}

// ---------------- front: keys+hists+degrees+bits (blocks 0..511) + all conversions (512..1911) ----------------
__global__ void front_k(const int* __restrict__ ei,
                        unsigned* __restrict__ keys1, unsigned* __restrict__ keys2,
                        unsigned* __restrict__ hist1, unsigned* __restrict__ hist2,
                        unsigned* __restrict__ indeg, unsigned* __restrict__ outdeg,
                        unsigned* __restrict__ bits,
                        const float* __restrict__ x, unsigned short* __restrict__ x_bf,
                        unsigned short* __restrict__ xT_bf,
                        const float* __restrict__ W0, unsigned short* __restrict__ WT0,
                        const float* __restrict__ W1, unsigned short* __restrict__ WT1,
                        const float* __restrict__ W2, unsigned short* __restrict__ WT2,
                        const float* __restrict__ fcW, unsigned short* __restrict__ fcWT){
  int b = blockIdx.x, t = threadIdx.x;
  if (b < 512){
    unsigned e = b*256u + t;
    K2 r1 = tf2x32(SK1A, SK1B, 0u, e);
    unsigned k1 = r1.a ^ r1.b;
    K2 r2 = tf2x32(SK2A, SK2B, 0u, e);
    unsigned k2 = r2.a ^ r2.b;
    keys1[e] = k1; keys2[e] = k2;
    atomicAdd(&hist1[k1>>16], 1u);
    atomicAdd(&hist2[k2>>16], 1u);
    unsigned s = (unsigned)ei[e], d = (unsigned)ei[NE+e];
    atomicAdd(&outdeg[s], 1u);
    atomicAdd(&indeg[d], 1u);
    atomicOr(&bits[d*128 + (s>>5)], 1u << (s&31));
    if (e < NN) atomicOr(&bits[e*128 + (e>>5)], 1u << (e&31));
    return;
  }
  int b2 = b - 512;
  if (b2 < 1024){                                       // x -> x_bf (flat, 4/thread)
    int i = b2*256 + t;
    float4 f = ((const float4*)x)[i];
    uint2 o;
    o.x = (unsigned)bf16rne(f.x) | ((unsigned)bf16rne(f.y)<<16);
    o.y = (unsigned)bf16rne(f.z) | ((unsigned)bf16rne(f.w)<<16);
    ((uint2*)x_bf)[i] = o;
  } else if (b2 < 1280){                                // x^T: 256 tiles
    int idx = b2 - 1024;
    tconv(x, xT_bf, NN, DIN, (idx>>2)*64, (idx&3)*64);
  } else if (b2 < 1376){                                // 3 enc weights: 32 tiles each
    int idx = b2 - 1280;
    int z = idx >> 5, tl = idx & 31;
    const float* src = z==0?W0 : z==1?W1 : W2;
    unsigned short* dst = z==0?WT0 : z==1?WT1 : WT2;
    tconv(src, dst, DIN, DHID, (tl>>3)*64, (tl&7)*64);
  } else {                                              // fcW: 24 tiles
    int by = b2 - 1376;
    tconv(fcW, fcWT, DCAT, DOUT, by*64, 0);
  }
}

// ---------------- 3-phase quad exclusive scan (y: 0=hist1,1=hist2,2=indeg,3=outdeg) ----------------
__global__ void scanA_k(const unsigned* __restrict__ in0, const unsigned* __restrict__ in1,
                        const unsigned* __restrict__ in2, const unsigned* __restrict__ in3,
                        unsigned* __restrict__ o0, unsigned* __restrict__ o1,
                        unsigned* __restrict__ o2, unsigned* __restrict__ o3,
                        unsigned* __restrict__ bsum){
  int y = blockIdx.y;
  int n = (y<2) ? NBINS : NN;
  if ((int)blockIdx.x*256 >= n) return;
  const unsigned* in = y==0?in0 : y==1?in1 : y==2?in2 : in3;
  unsigned* o        = y==0?o0  : y==1?o1  : y==2?o2  : o3;
  __shared__ unsigned s[256];
  int t = threadIdx.x; unsigned i = blockIdx.x*256u + t;
  unsigned v = in[i]; s[t] = v; __syncthreads();
  for (int off=1; off<256; off<<=1){
    unsigned u = (t>=off)?s[t-off]:0u; __syncthreads();
    s[t]+=u; __syncthreads();
  }
  o[i] = s[t]-v;
  if (t==255) bsum[y*256 + blockIdx.x] = s[255];
}
__global__ void scanB_k(unsigned* __restrict__ bsum){
  __shared__ unsigned s[256];
  int y = blockIdx.x, t = threadIdx.x;
  int nb = (y<2) ? 256 : 16;
  unsigned* b = bsum + y*256;
  unsigned v = (t<nb)?b[t]:0u; s[t]=v; __syncthreads();
  for (int off=1; off<256; off<<=1){
    unsigned u=(t>=off)?s[t-off]:0u; __syncthreads();
    s[t]+=u; __syncthreads();
  }
  if (t<nb) b[t]=s[t]-v;
}
// phase C + med1 fused (y==1: test median bin using hist2 value)
__global__ void scanC_k(unsigned* __restrict__ o0, unsigned* __restrict__ o1,
                        unsigned* __restrict__ o2, unsigned* __restrict__ o3,
                        unsigned* __restrict__ c0, unsigned* __restrict__ c1,
                        unsigned* __restrict__ c2, unsigned* __restrict__ c3,
                        const unsigned* __restrict__ bsum, const unsigned* __restrict__ hist2,
                        unsigned* __restrict__ med){
  int y = blockIdx.y;
  int n = (y<2) ? NBINS : NN;
  if ((int)blockIdx.x*256 >= n) return;
  unsigned* o = y==0?o0 : y==1?o1 : y==2?o2 : o3;
  unsigned* c = y==0?c0 : y==1?c1 : y==2?c2 : c3;
  unsigned i = blockIdx.x*256u + threadIdx.x;
  unsigned v = o[i] + bsum[y*256 + blockIdx.x];
  o[i]=v; c[i]=v;
  if (y==1){
    unsigned hv = hist2[i];
    if (v <= HALF_E && HALF_E < v + hv){ med[0] = i; med[1] = v; }
  }
}

// ---------------- scat1 + median-bin collection ----------------
__global__ void scat1med_k(const unsigned* __restrict__ keys1, const unsigned* __restrict__ keys2,
                           unsigned* __restrict__ cursor, unsigned* __restrict__ slow,
                           unsigned* __restrict__ stb, unsigned* __restrict__ med){
  int e = blockIdx.x*256 + threadIdx.x;
  unsigned k = keys1[e];
  unsigned p = atomicAdd(&cursor[k>>16], 1u);
  slow[p] = k & 0xFFFFu; stb[p] = (unsigned)e;
  unsigned k2 = keys2[e];
  if ((k2>>16) == med[0]){
    unsigned idx = atomicAdd(&med[2], 1u);
    if (idx < MED_CAP){ med[8+idx] = k2 & 0xFFFFu; med[72+idx] = (unsigned)e; }
  }
}

// ---------------- rank1 (blocks 0..EB-1) + med3 cut-selection (block EB) ----------------
__global__ void rank1med_k(const unsigned* __restrict__ keys1, const unsigned* __restrict__ prefix,
                           const unsigned* __restrict__ hist, const unsigned* __restrict__ slow,
                           const unsigned* __restrict__ stb, unsigned* __restrict__ rank1,
                           unsigned* __restrict__ med){
  int b = blockIdx.x, t = threadIdx.x;
  if (b == NE/256){
    unsigned n = med[2]; if (n > MED_CAP) n = MED_CAP;
    unsigned qcut = HALF_E - med[1];
    if (t < (int)n){
      unsigned lo = med[8+t], rk = med[72+t], pos = 0;
      for (unsigned j=0;j<n;j++){
        unsigned lj = med[8+j], rj = med[72+j];
        if (lj < lo || (lj==lo && rj < rk)) pos++;
      }
      if (pos == qcut){ med[3] = lo; med[4] = rk; }
    }
    return;
  }
  int e = b*256 + t;
  unsigned k = keys1[e], h = k>>16, lo = k & 0xFFFFu, tb = (unsigned)e;
  unsigned base = prefix[h], n = hist[h], r = 0;
  for (unsigned j=0;j<n;j++){
    unsigned l2 = slow[base+j], t2 = stb[base+j];
    if (l2 < lo || (l2==lo && t2 < tb)) r++;
  }
  rank1[e] = base + r;
}

// ---------------- CSR scatter + inline keep ----------------
__global__ void scatter_edges_k(const int* __restrict__ ei, const unsigned* __restrict__ rank1,
                                const unsigned* __restrict__ keys2, const unsigned* __restrict__ med,
                                unsigned* __restrict__ curin, unsigned* __restrict__ curout,
                                unsigned* __restrict__ in_list, unsigned* __restrict__ out_list){
  int e = blockIdx.x*256 + threadIdx.x;
  unsigned s = (unsigned)ei[e], d = (unsigned)ei[NE+e];
  unsigned rk = rank1[e], k2 = keys2[rk];
  unsigned h = k2>>16, lo = k2 & 0xFFFFu;
  unsigned hs = med[0], loc = med[3], rkc = med[4];
  unsigned keep = (h > hs) || (h == hs && (lo > loc || (lo == loc && rk >= rkc)));
  unsigned p = atomicAdd(&curin[d], 1u);  in_list[p] = s;
  unsigned q = atomicAdd(&curout[s], 1u); out_list[q] = d | (keep<<31);
}

// ---------------- 2-hop reach+popcount (blocks 0..4095) + cut feature (blocks 4096..8191) ----------------
__global__ void reachcut_k(const unsigned* __restrict__ bits, const unsigned* __restrict__ in_off,
                           const unsigned* __restrict__ in_list, const unsigned* __restrict__ indeg,
                           unsigned* __restrict__ reach, float* __restrict__ cntinv,
                           const float* __restrict__ x, const unsigned* __restrict__ out_off,
                           const unsigned* __restrict__ outdeg, const unsigned* __restrict__ out_list,
                           unsigned short* __restrict__ cut_bf){
  int b = blockIdx.x, t = threadIdx.x;
  if (b < NN){
    __shared__ int ws4[4];
    int i = b;
    int c = 0;
    if (t < 128){
      unsigned off = in_off[i], deg = indeg[i];
      unsigned acc = bits[i*128 + t];
      for (unsigned j=0;j<deg;j++) acc |= bits[in_list[off+j]*128 + t];
      reach[i*128 + t] = acc;
      c = __popc(acc);
    }
    for (int o=32;o>0;o>>=1) c += __shfl_xor(c, o, 64);
    if ((t&63)==0) ws4[t>>6] = c;
    __syncthreads();
    if (t==0) cntinv[i] = 1.0f / (float)(ws4[0]+ws4[1]+ws4[2]+ws4[3]);
  } else {
    int s = b - NN;
    unsigned off = out_off[s], deg = outdeg[s];
    float acc = 0.f; int cnt = 0;
    for (unsigned j=0;j<deg;j++){
      unsigned p = out_list[off+j];
      if (p >> 31){ cnt++; acc += x[(p & 0xFFFFu)*DIN + t]; }
    }
    float v = cnt ? acc / (float)cnt : x[s*DIN + t];
    cut_bf[(size_t)s*DIN + t] = bf16rne(v);
  }
}

// ---------------- ego bit-GEMM, split-K=4, K_STEP=128 ----------------
__global__ void bitgemm_k(const unsigned* __restrict__ reach, const unsigned short* __restrict__ xT,
                          float* __restrict__ pbuf){
  __shared__ __align__(16) unsigned short bt[4][64*32];
  int t = threadIdx.x, w = t>>6, l = t&63;
  int m0 = blockIdx.x*64, n0 = blockIdx.y*64;
  int kbase = blockIdx.z*(NN/4);
  int srow = t>>2, sg = t&3;
  int arow = m0 + 16*w + (l&15);
  int lg = l>>4;
  f32x4 acc[4];
  #pragma unroll
  for (int c=0;c<4;c++) acc[c] = f32x4{0.f,0.f,0.f,0.f};

  for (int it=0; it<8; ++it){
    int kk = kbase + it*128;
    __syncthreads();
    #pragma unroll
    for (int s=0;s<4;s++){
      uint4 v = *(const uint4*)&xT[(size_t)(n0+srow)*NN + kk + 32*s + sg*8];
      *(uint4*)&bt[s][srow*32 + ((sg ^ (srow&3))*8)] = v;
    }
    __syncthreads();
    unsigned rw[4];
    *(uint4*)rw = *(const uint4*)&reach[(size_t)arow*128 + (kk>>5)];
    #pragma unroll
    for (int s=0;s<4;s++){
      unsigned byte = (rw[s] >> (8*lg)) & 0xFFu;
      union { short8 s8; unsigned u[4]; } af;
      #pragma unroll
      for (int pp=0;pp<4;pp++){
        unsigned b0 = (byte>>(2*pp))&1u, b1 = (byte>>(2*pp+1))&1u;
        af.u[pp] = b0*0x3F80u | b1*0x3F800000u;
      }
      #pragma unroll
      for (int c=0;c<4;c++){
        int brow = 16*c + (l&15);
        short8 bf = *(const short8*)&bt[s][brow*32 + ((lg ^ (brow&3))*8)];
        acc[c] = __builtin_amdgcn_mfma_f32_16x16x32_bf16(af.s8, bf, acc[c], 0,0,0);
      }
    }
  }
  size_t zoff = (size_t)blockIdx.z*NN*DIN;
  #pragma unroll
  for (int c=0;c<4;c++){
    #pragma unroll
    for (int r=0;r<4;r++){
      int row = m0 + 16*w + 4*lg + r;
      int col = n0 + 16*c + (l&15);
      pbuf[zoff + (size_t)row*DIN + col] = acc[c][r];
    }
  }
}

// ---------------- reduce partials + scale -> ego_bf ----------------
__global__ void redscale_k(const float* __restrict__ pbuf, const float* __restrict__ cntinv,
                           unsigned short* __restrict__ ego_bf){
  int g = blockIdx.x*256 + threadIdx.x;
  const size_t S = (size_t)NN*DIN/4;
  const float4* p4 = (const float4*)pbuf;
  float4 a = p4[g], b = p4[g+S], c = p4[g+2*S], d = p4[g+3*S];
  int row = (g*4)>>8;
  float ci = cntinv[row];
  float vx = (a.x+b.x+c.x+d.x)*ci, vy = (a.y+b.y+c.y+d.y)*ci;
  float vz = (a.z+b.z+c.z+d.z)*ci, vw = (a.w+b.w+c.w+d.w)*ci;
  uint2 o;
  o.x = (unsigned)bf16rne(vx) | ((unsigned)bf16rne(vy)<<16);
  o.y = (unsigned)bf16rne(vz) | ((unsigned)bf16rne(vw)<<16);
  ((uint2*)ego_bf)[g] = o;
}

// ---------------- aggregate 256-dim features over in-edges (linearity trick) ----------------
__global__ void aggfeat_k(const unsigned short* __restrict__ ego_bf, const unsigned short* __restrict__ cut_bf,
                          const unsigned* __restrict__ in_off, const unsigned* __restrict__ indeg,
                          const unsigned* __restrict__ in_list,
                          unsigned short* __restrict__ aggE, unsigned short* __restrict__ aggC){
  int i = blockIdx.x, t = threadIdx.x;
  unsigned off = in_off[i], deg = indeg[i];
  float ae = 0.f, ac = 0.f;
  for (unsigned j=0;j<deg;j++){
    unsigned s = in_list[off+j];
    ae += bf2f(ego_bf[(size_t)s*DIN + t]);
    ac += bf2f(cut_bf[(size_t)s*DIN + t]);
  }
  aggE[(size_t)i*DIN + t] = bf16rne(ae);
  aggC[(size_t)i*DIN + t] = bf16rne(ac);
}

// ---------------- merged encoder GEMM (z: 0=ego-agg,1=cut-agg,2=glob) ----------------
__global__ void gemm3_k(const unsigned short* __restrict__ aggE, const unsigned short* __restrict__ aggC,
                        const unsigned short* __restrict__ xbf,
                        const unsigned short* __restrict__ WTe, const unsigned short* __restrict__ WTc,
                        const unsigned short* __restrict__ WTg,
                        const float* __restrict__ eb, const float* __restrict__ cb, const float* __restrict__ gb,
                        const unsigned* __restrict__ indeg, unsigned short* __restrict__ hcat){
  __shared__ __align__(16) unsigned short at[4][64*32];
  __shared__ __align__(16) unsigned short bt[4][64*32];
  int z = blockIdx.z;
  const unsigned short* A  = z==0? aggE : z==1? aggC : xbf;
  const unsigned short* BT = z==0? WTe  : z==1? WTc  : WTg;
  const float* bias        = z==0? eb   : z==1? cb   : gb;
  int t = threadIdx.x, w = t>>6, l = t&63;
  int n0 = blockIdx.x*64, m0 = blockIdx.y*64;
  int srow = t>>2, sg = t&3;
  int lg = l>>4;
  f32x4 acc[4];
  #pragma unroll
  for (int c=0;c<4;c++) acc[c] = f32x4{0.f,0.f,0.f,0.f};

  for (int it=0; it<2; ++it){
    int kk = it*128;
    __syncthreads();
    #pragma unroll
    for (int s=0;s<4;s++){
      uint4 va = *(const uint4*)&A [(size_t)(m0+srow)*DIN + kk + 32*s + sg*8];
      uint4 vb = *(const uint4*)&BT[(size_t)(n0+srow)*DIN + kk + 32*s + sg*8];
      *(uint4*)&at[s][srow*32 + ((sg ^ (srow&3))*8)] = va;
      *(uint4*)&bt[s][srow*32 + ((sg ^ (srow&3))*8)] = vb;
    }
    __syncthreads();
    int ar = 16*w + (l&15);
    #pragma unroll
    for (int s=0;s<4;s++){
      short8 af = *(const short8*)&at[s][ar*32 + ((lg ^ (ar&3))*8)];
      #pragma unroll
      for (int c=0;c<4;c++){
        int brow = 16*c + (l&15);
        short8 bf = *(const short8*)&bt[s][brow*32 + ((lg ^ (brow&3))*8)];
        acc[c] = __builtin_amdgcn_mfma_f32_16x16x32_bf16(af, bf, acc[c], 0,0,0);
      }
    }
  }
  #pragma unroll
  for (int c=0;c<4;c++){
    #pragma unroll
    for (int r=0;r<4;r++){
      int row = m0 + 16*w + 4*lg + r;
      int col = n0 + 16*c + (l&15);
      float scale = (z<2) ? (float)indeg[row] : 1.0f;
      float v = acc[c][r] + bias[col]*scale;
      if (z<2) v = fmaxf(v, 0.f);
      hcat[(size_t)row*DCAT + z*DHID + col] = bf16rne(v);
    }
  }
}

// ---------------- fc GEMM full-K + fused bias + log_softmax ----------------
// grid NN/64 blocks; each block computes rows m0..m0+63 x all 64 cols over K=1536.
__global__ void fcsm_k(const unsigned short* __restrict__ hcat, const unsigned short* __restrict__ fcWT,
                       const float* __restrict__ fcb, float* __restrict__ out){
  __shared__ __align__(16) unsigned short at[4][64*32];
  __shared__ __align__(16) unsigned short bt[4][64*32];
  int t = threadIdx.x, w = t>>6, l = t&63;
  int m0 = blockIdx.x*64;
  int srow = t>>2, sg = t&3;
  int lg = l>>4;
  f32x4 acc[4];
  #pragma unroll
  for (int c=0;c<4;c++) acc[c] = f32x4{0.f,0.f,0.f,0.f};

  for (int it=0; it<12; ++it){
    int kk = it*128;
    __syncthreads();
    #pragma unroll
    for (int s=0;s<4;s++){
      uint4 va = *(const uint4*)&hcat [(size_t)(m0+srow)*DCAT + kk + 32*s + sg*8];
      uint4 vb = *(const uint4*)&fcWT[(size_t)srow*DCAT + kk + 32*s + sg*8];
      *(uint4*)&at[s][srow*32 + ((sg ^ (srow&3))*8)] = va;
      *(uint4*)&bt[s][srow*32 + ((sg ^ (srow&3))*8)] = vb;
    }
    __syncthreads();
    int ar = 16*w + (l&15);
    #pragma unroll
    for (int s=0;s<4;s++){
      short8 af = *(const short8*)&at[s][ar*32 + ((lg ^ (ar&3))*8)];
      #pragma unroll
      for (int c=0;c<4;c++){
        int brow = 16*c + (l&15);
        short8 bf = *(const short8*)&bt[s][brow*32 + ((lg ^ (brow&3))*8)];
        acc[c] = __builtin_amdgcn_mfma_f32_16x16x32_bf16(af, bf, acc[c], 0,0,0);
      }
    }
  }
  // epilogue: rows m0+16w+4lg+r live in the 16-lane group (l&15 = col low bits, c = col high bits)
  #pragma unroll
  for (int r=0;r<4;r++){
    int row = m0 + 16*w + 4*lg + r;
    float v0 = acc[0][r] + fcb[(l&15)];
    float v1 = acc[1][r] + fcb[16 + (l&15)];
    float v2 = acc[2][r] + fcb[32 + (l&15)];
    float v3 = acc[3][r] + fcb[48 + (l&15)];
    float m = fmaxf(fmaxf(v0,v1), fmaxf(v2,v3));
    m = fmaxf(m, __shfl_xor(m, 1, 64));
    m = fmaxf(m, __shfl_xor(m, 2, 64));
    m = fmaxf(m, __shfl_xor(m, 4, 64));
    m = fmaxf(m, __shfl_xor(m, 8, 64));
    float s = __expf(v0-m) + __expf(v1-m) + __expf(v2-m) + __expf(v3-m);
    s += __shfl_xor(s, 1, 64);
    s += __shfl_xor(s, 2, 64);
    s += __shfl_xor(s, 4, 64);
    s += __shfl_xor(s, 8, 64);
    float ls = logf(s);
    size_t ro = (size_t)row*DOUT + (l&15);
    out[ro]      = (v0 - m) - ls;
    out[ro + 16] = (v1 - m) - ls;
    out[ro + 32] = (v2 - m) - ls;
    out[ro + 48] = (v3 - m) - ls;
  }
}

// ---------------- host launch ----------------
static inline size_t alignup(size_t x){ return (x + 255) & ~(size_t)255; }

extern "C" void kernel_launch(void* const* d_in, const int* in_sizes, int n_in,
                              void* d_out, int out_size, void* d_ws, size_t ws_size,
                              hipStream_t stream) {
  const float* x      = (const float*)d_in[0];
  const int*   ei     = (const int*)  d_in[1];
  const float* ego_W  = (const float*)d_in[2];
  const float* ego_b  = (const float*)d_in[3];
  const float* cut_W  = (const float*)d_in[4];
  const float* cut_b  = (const float*)d_in[5];
  const float* glob_W = (const float*)d_in[6];
  const float* glob_b = (const float*)d_in[7];
  const float* fc_W   = (const float*)d_in[8];
  const float* fc_b   = (const float*)d_in[9];
  float* out = (float*)d_out;

  char* base = (char*)d_ws;
  char* p = base;
  #define ALLOC(ty, name, cnt) ty* name = (ty*)p; p += alignup(sizeof(ty)*(size_t)(cnt));
  ALLOC(char,           R0,      (size_t)4*NN*DIN*4);   // 16MB: sort temps -> pbuf -> hcat
  // ---- zero region (one memset) ----
  ALLOC(unsigned,       bits,    NN*128);
  ALLOC(unsigned,       indeg,   NN);
  ALLOC(unsigned,       outdeg,  NN);
  ALLOC(unsigned,       hist1,   NBINS);
  ALLOC(unsigned,       hist2,   NBINS);
  ALLOC(unsigned,       med,     256);
  char* zero_end = p;
  // ---- rest ----
  ALLOC(unsigned,       in_off,  NN);
  ALLOC(unsigned,       out_off, NN);
  ALLOC(unsigned,       curin,   NN);
  ALLOC(unsigned,       curout,  NN);
  ALLOC(unsigned,       in_list, NE);
  ALLOC(unsigned,       out_list,NE);
  ALLOC(unsigned,       reach,   NN*128);
  ALLOC(float,          cntinv,  NN);
  ALLOC(unsigned short, x_bf,    (size_t)NN*DIN);
  ALLOC(unsigned short, xT_bf,   (size_t)DIN*NN);
  ALLOC(unsigned short, ego_bf,  (size_t)NN*DIN);
  ALLOC(unsigned short, cut_bf,  (size_t)NN*DIN);
  ALLOC(unsigned short, aggE_bf, (size_t)NN*DIN);
  ALLOC(unsigned short, aggC_bf, (size_t)NN*DIN);
  ALLOC(unsigned short, egoWT,   (size_t)DHID*DIN);
  ALLOC(unsigned short, cutWT,   (size_t)DHID*DIN);
  ALLOC(unsigned short, globWT,  (size_t)DHID*DIN);
  ALLOC(unsigned short, fcWT,    (size_t)DOUT*DCAT);
  ALLOC(unsigned,       prefix1, NBINS);
  ALLOC(unsigned,       cursor1, NBINS);
  ALLOC(unsigned,       prefix2, NBINS);
  ALLOC(unsigned,       cursor2, NBINS);
  ALLOC(unsigned,       bsum,    1024);
  #undef ALLOC
  size_t need = (size_t)(p - base);
  if (ws_size < need){
    hipMemsetAsync(d_out, 0x7F, (size_t)out_size*sizeof(float), stream);
    return;
  }
  float*          pbuf = (float*)R0;
  unsigned short* hcat = (unsigned short*)R0;
  char* q = R0;
  #define OALLOC(ty, name, cnt) ty* name = (ty*)q; q += alignup(sizeof(ty)*(size_t)(cnt));
  OALLOC(unsigned, keys1,  NE);
  OALLOC(unsigned, keys2,  NE);
  OALLOC(unsigned, rank1,  NE);
  OALLOC(unsigned, slow,   NE);
  OALLOC(unsigned, stb,    NE);
  #undef OALLOC

  const int EB = NE/256;

  // 1) zero [bits|indeg|outdeg|hist1|hist2|med]
  hipMemsetAsync(bits, 0, (size_t)(zero_end - (char*)bits), stream);
  // 2) keys + hists + degrees + bits, fused with ALL conversions
  hipLaunchKernelGGL(front_k, dim3(1912), dim3(256), 0, stream,
                     ei, keys1, keys2, hist1, hist2, indeg, outdeg, bits,
                     x, x_bf, xT_bf, ego_W, egoWT, cut_W, cutWT, glob_W, globWT, fc_W, fcWT);
  // 3-5) quad 3-phase scan; med1 fused into scanC
  hipLaunchKernelGGL(scanA_k, dim3(NBINS/256, 4), dim3(256), 0, stream,
                     hist1, hist2, indeg, outdeg, prefix1, prefix2, in_off, out_off, bsum);
  hipLaunchKernelGGL(scanB_k, dim3(4), dim3(256), 0, stream, bsum);
  hipLaunchKernelGGL(scanC_k, dim3(NBINS/256, 4), dim3(256), 0, stream,
                     prefix1, prefix2, in_off, out_off, cursor1, cursor2, curin, curout,
                     bsum, hist2, med);
  // 6) round-1 binned scatter + median-bin member collection
  hipLaunchKernelGGL(scat1med_k, dim3(EB), dim3(256), 0, stream,
                     keys1, keys2, cursor1, slow, stb, med);
  // 7) round-1 rank + cut-element selection
  hipLaunchKernelGGL(rank1med_k, dim3(EB+1), dim3(256), 0, stream,
                     keys1, prefix1, hist1, slow, stb, rank1, med);
  // 8) CSR scatter + inline keep
  hipLaunchKernelGGL(scatter_edges_k, dim3(EB), dim3(256), 0, stream,
                     ei, rank1, keys2, med, curin, curout, in_list, out_list);
  // 9) 2-hop reach + cut feature
  hipLaunchKernelGGL(reachcut_k, dim3(2*NN), dim3(256), 0, stream,
                     bits, in_off, in_list, indeg, reach, cntinv,
                     x, out_off, outdeg, out_list, cut_bf);
  // 10) ego bit-GEMM (pbuf overlays sort temps; keys2/rank1 dead after step 8)
  hipLaunchKernelGGL(bitgemm_k, dim3(NN/64, DIN/64, 4), dim3(256), 0, stream, reach, xT_bf, pbuf);
  // 11) reduce partials + scale
  hipLaunchKernelGGL(redscale_k, dim3((NN*DIN/4)/256), dim3(256), 0, stream, pbuf, cntinv, ego_bf);
  // 12) feature aggregation (linearity trick)
  hipLaunchKernelGGL(aggfeat_k, dim3(NN), dim3(256), 0, stream,
                     ego_bf, cut_bf, in_off, indeg, in_list, aggE_bf, aggC_bf);
  // 13) encoders -> hcat (overlays pbuf, dead after 11)
  hipLaunchKernelGGL(gemm3_k, dim3(DHID/64, NN/64, 3), dim3(256), 0, stream,
                     aggE_bf, aggC_bf, x_bf, egoWT, cutWT, globWT,
                     ego_b, cut_b, glob_b, indeg, hcat);
  // 14) fc full-K + fused bias + log_softmax
  hipLaunchKernelGGL(fcsm_k, dim3(NN/64), dim3(256), 0, stream, hcat, fcWT, fc_b, out);
}